// Round 2
// baseline (3909.343 us; speedup 1.0000x reference)
//
#include <hip/hip_runtime.h>
#include <stdint.h>
#include <stddef.h>

#define CH     512
#define TT     32
#define NBLK   32
#define NBATCH 32
#define NCHUNK 8      // WGs per batch (64 channels each)
#define NTHR   1024   // 16 waves, 4 per SIMD

// ---- transpose: WT[j][c] = W[c][j] (row j = presyn channel, 2 KiB/row) ----
__global__ __launch_bounds__(256) void transpose_k(const float* __restrict__ W,
                                                   float* __restrict__ WT) {
    __shared__ float tile[64][65];
    const int bx = blockIdx.x & 7, by = blockIdx.x >> 3;
    const int lx = threadIdx.x & 63, ly = threadIdx.x >> 6;
    for (int r = ly; r < 64; r += 4)
        tile[r][lx] = W[(size_t)(by * 64 + r) * CH + bx * 64 + lx];
    __syncthreads();
    for (int r = ly; r < 64; r += 4)
        WT[(size_t)(bx * 64 + r) * CH + by * 64 + lx] = tile[lx][r];
}

// published word: two 16b entries [tag4 | t6 | ch6]; t=63 = no spike.
// Words for block n go to parity slot (n&1); consumers of block n read (n-1)&1.
// flag[kown] = n+1 (monotone) released AFTER the words -> full msg-passing order.
// Parity double-buffer closes the overwrite race: the only writer of the parity
// a consumer reads is a producer finishing block n+1, which requires this
// consumer's own block-n publish first.
__global__ __launch_bounds__(NTHR, 4) void snn_kernel(
    const float* __restrict__ x,
    const float* __restrict__ beta_raw,
    const float* __restrict__ WT,
    const float* __restrict__ p_raw,
    const float* __restrict__ b_raw,
    int*       __restrict__ ent_g,     // [NBATCH][2][256] parity-buffered words
    int*       __restrict__ flag_g,    // [NBATCH][16] padded ready flags
    float*     __restrict__ out)
{
    __shared__ float rec8[8][2112];    // [gather-wave][l*33+t]; rec8[0] x-seeded
    __shared__ float rec_tot[2112];
    __shared__ int   tf_lds[64];
    __shared__ int   tmp16[64];        // producer sort scratch

    const int bidx = blockIdx.x;
    const int b    = bidx & (NBATCH - 1);   // batch's 8 WGs share an XCD
    const int kown = bidx >> 5;             // channel chunk 0..7
    const int tid  = threadIdx.x;
    const int l    = tid & 63;
    const int g    = tid >> 6;              // wave 0..15
    const size_t base = ((size_t)b) << 19;  // b*CH*1024 floats
    int* pg = ent_g  + (b << 9);            // 512 words (2 parities x 256)
    int* fg = flag_g + (b << 4);

    const int c = (kown << 6) + l;          // wave0-lane channel
    const float beta  = fminf(fmaxf(beta_raw[c], 0.001f), 0.999f);
    const float p     = fminf(fabsf(p_raw[c]), 0.999f);
    const float bb    = fminf(fmaxf(fabsf(b_raw[c]), 0.001f), 1.0f);
    const float inv_p = 1.0f / p;
    float p32; { float t2 = p*p, t4 = t2*t2, t8 = t4*t4, t16 = t8*t8; p32 = t16*t16; }
    float a_mult = 0.f, v_init = 0.f;
    int   zero_start = 0;
    const unsigned long long lowmask = (1ull << l) - 1ull;

    // ---- pre-loop: seed rec8[0] with x block 0; zero rec8[1..7] ----
    if (tid < 512) {
        const int ch = tid >> 3, q = tid & 7;
        const float4 v = *(const float4*)(x + base + ((size_t)((kown << 6) + ch) << 10) + (q << 2));
        float* d = &rec8[0][ch * 33 + (q << 2)];
        d[0] = v.x; d[1] = v.y; d[2] = v.z; d[3] = v.w;
    } else {
        const int t0 = tid - 512;
        #pragma unroll
        for (int z = 0; z < 29; ++z) {
            const int k = t0 + (z << 9);
            if (k < 14784) (&rec8[1][0])[k] = 0.f;
        }
    }
    __syncthreads();

    for (int n = 0; n < NBLK; ++n) {
        // ---- C: waves 0-7 flag-gated incremental gather (fixed chunk order)
        //         waves 8-15: x(n+1) prefetch + out(n-1) store ----
        float4 xstage;
        if (g >= 8) {
            const int slot = tid - 512;
            const int ch = slot >> 3, q = slot & 7;
            if (n + 1 < NBLK)
                xstage = *(const float4*)(x + base + ((size_t)((kown << 6) + ch) << 10) + ((n + 1) << 5) + (q << 2));
            if (n > 0) {
                const int tf = tf_lds[ch];
                const int t0 = q << 2;
                float4 v;
                v.x = (t0     == tf) ? 1.f : 0.f;
                v.y = (t0 + 1 == tf) ? 1.f : 0.f;
                v.z = (t0 + 2 == tf) ? 1.f : 0.f;
                v.w = (t0 + 3 == tf) ? 1.f : 0.f;
                *(float4*)(out + base + ((size_t)((kown << 6) + ch) << 10) + ((n - 1) << 5) + t0) = v;
            }
        } else if (n > 0) {
            const int* pgr = pg + (((n - 1) & 1) << 8);   // read parity
            const int l31 = l & 31;
            const char* WTb = (const char*)WT;
            const int col4 = ((kown << 6) + l) << 2;
            float* myrec = &rec8[g][l * 33];
            int pf = 0;                 // global prefix over chunks
            float acc = 0.f; int cur_t = -1;
            #pragma unroll 1
            for (int j = 0; j < 8; ++j) {
                // wait for chunk j's block-(n-1) publish (monotone flag)
                while (__hip_atomic_load(fg + j, __ATOMIC_RELAXED, __HIP_MEMORY_SCOPE_AGENT) < n)
                    __builtin_amdgcn_s_sleep(1);
                __builtin_amdgcn_fence(__ATOMIC_ACQUIRE, "agent");
                // lane l holds word (l&31); ranks r: word r>>1, half r&1
                const int wv = __hip_atomic_load(pgr + (j << 5) + l31,
                                                 __ATOMIC_RELAXED, __HIP_MEMORY_SCOPE_AGENT);
                const int elo = wv & 0xFFFF, ehi = (wv >> 16) & 0xFFFF;
                const unsigned long long blo = __ballot((l < 32) && (((elo >> 6) & 63) != 63));
                const unsigned long long bhi = __ballot((l < 32) && (((ehi >> 6) & 63) != 63));
                const int cnt = (int)__popcll(blo) + (int)__popcll(bhi);
                // my global indices gi ≡ g (mod 8) in [pf, pf+cnt) -> same per-wave
                // sequence as the old segment loop (determinism preserved)
                const int off   = (g - pf) & 7;
                const int mycnt = (cnt > off) ? ((cnt - off + 7) >> 3) : 0;
                int T[8]; float F[8];
                #pragma unroll
                for (int k = 0; k < 8; ++k) {
                    const int r  = off + (k << 3);          // chunk-local rank
                    const bool ok = k < mycnt;
                    const int w  = __builtin_amdgcn_readlane(wv, r >> 1);
                    const int e  = (r & 1) ? ((w >> 16) & 0xFFFF) : (w & 0xFFFF);
                    T[k] = ok ? ((e >> 6) & 31) : -1;
                    const int ch = ok ? ((j << 6) | (e & 63)) : 0;
                    F[k] = *(const float*)(WTb + (ch << 11) + col4);
                }
                #pragma unroll
                for (int k = 0; k < 8; ++k) {
                    if (T[k] >= 0) {
                        if (T[k] != cur_t) { if (cur_t >= 0) myrec[cur_t] += acc; acc = 0.f; cur_t = T[k]; }
                        acc += F[k];
                    }
                }
                pf += cnt;
            }
            if (cur_t >= 0) myrec[cur_t] += acc;
        }
        __syncthreads();   // B3: partials complete

        // ---- D: reduce 8 partials (x seeded in rec8[0]); all 1024 threads ----
        #pragma unroll
        for (int r = 0; r < 2; ++r) {
            const int e = tid + (r << 10);
            const int idx = ((e >> 5) * 33) + (e & 31);
            rec_tot[idx] = ((rec8[0][idx] + rec8[1][idx]) + (rec8[2][idx] + rec8[3][idx]))
                         + ((rec8[4][idx] + rec8[5][idx]) + (rec8[6][idx] + rec8[7][idx]));
        }
        __syncthreads();   // B4: rec_tot ready

        // ---- E: dynamics+publish (wave 0, prio 1, fused spike-rank)
        //         | x-seed write (waves 8-15) | zero (waves 1-7) ----
        if (g == 0) {
            __builtin_amdgcn_s_setprio(1);
            float mem = 0.f, pc = p, pca = p;
            int t_first = -1, mypos = 0;
            unsigned prefc = 0;
            #pragma unroll
            for (int t = 0; t < TT; ++t) {
                const float rv = rec_tot[l * 33 + t];
                float cur = (t >= zero_start) ? rv : 0.f;
                if (t == 0) cur += beta * v_init;
                mem = beta * mem + cur;
                const float vth = 1.f + bb * pc * a_mult;
                const bool fire = (mem - vth > 0.f) && (t_first < 0);
                const unsigned long long bal = __ballot(fire);
                if (fire) {
                    t_first = t; pca = pc;
                    mypos = (int)prefc + (int)__popcll(bal & lowmask);
                }
                prefc += (unsigned)__popcll(bal);
                pc *= p;
            }
            if (t_first >= 0) {
                float pd = 1.f;
                for (int m = 31 - t_first; m > 0; --m) pd *= p;
                a_mult = (pca * a_mult + inv_p) * pd;
                v_init = 0.f; zero_start = t_first;
            } else {
                a_mult = p32 * a_mult;
                v_init = mem; zero_start = 0;
            }
            tf_lds[l] = t_first;
            if (n + 1 < NBLK) {
                const bool sp = (t_first >= 0);
                const unsigned long long balS = __ballot(sp);
                const int cntS = (int)prefc;
                if (!sp) mypos = cntS + (int)__popcll(~balS & lowmask);
                const int tval = sp ? t_first : 63;
                tmp16[mypos] = ((n & 15) << 12) | (tval << 6) | l;
                __threadfence_block();   // drain ds_write before cross-lane ds_read
                if (l < 32) {
                    const int wlo = tmp16[l << 1];
                    const int whi = tmp16[(l << 1) | 1];
                    __hip_atomic_store(pg + ((n & 1) << 8) + (kown << 5) + l, wlo | (whi << 16),
                                       __ATOMIC_RELAXED, __HIP_MEMORY_SCOPE_AGENT);
                }
                __builtin_amdgcn_fence(__ATOMIC_RELEASE, "agent");   // words -> L2
                if (l == 0)
                    __hip_atomic_store(fg + kown, n + 1,
                                       __ATOMIC_RELAXED, __HIP_MEMORY_SCOPE_AGENT);
            }
            __builtin_amdgcn_s_setprio(0);
        } else if (g >= 8) {
            if (n + 1 < NBLK) {
                const int slot = tid - 512;
                const int ch = slot >> 3, q = slot & 7;
                float* d = &rec8[0][ch * 33 + (q << 2)];
                d[0] = xstage.x; d[1] = xstage.y; d[2] = xstage.z; d[3] = xstage.w;
            }
        } else {
            if (n + 1 < NBLK) {
                const int t0 = tid - 64;
                #pragma unroll
                for (int z = 0; z < 33; ++z)
                    (&rec8[1][0])[t0 + 448 * z] = 0.f;
            }
        }
        __syncthreads();   // B5
    }

    // ---- final out block 31 ----
    if (tid < 512) {
        const int ch = tid >> 3, q = tid & 7;
        const int tf = tf_lds[ch];
        const int t0 = q << 2;
        float4 v;
        v.x = (t0     == tf) ? 1.f : 0.f;
        v.y = (t0 + 1 == tf) ? 1.f : 0.f;
        v.z = (t0 + 2 == tf) ? 1.f : 0.f;
        v.w = (t0 + 3 == tf) ? 1.f : 0.f;
        *(float4*)(out + base + ((size_t)((kown << 6) + ch) << 10) + (31 << 5) + t0) = v;
    }
}

extern "C" void kernel_launch(void* const* d_in, const int* in_sizes, int n_in,
                              void* d_out, int out_size, void* d_ws, size_t ws_size,
                              hipStream_t stream) {
    (void)in_sizes; (void)n_in; (void)out_size;
    const float* x   = (const float*)d_in[0];
    const float* br  = (const float*)d_in[1];
    const float* W   = (const float*)d_in[2];
    const float* pr  = (const float*)d_in[3];
    const float* bbr = (const float*)d_in[4];
    float* out = (float*)d_out;

    const size_t wt_bytes   = (size_t)CH * CH * sizeof(float);      // 1 MiB
    const size_t ent_bytes  = (size_t)NBATCH * 512 * sizeof(int);   // 64 KiB (2 parities)
    const size_t flag_bytes = (size_t)NBATCH * 16 * sizeof(int);    // 2 KiB
    if (ws_size < wt_bytes + ent_bytes + flag_bytes) return;

    float* WT     = (float*)d_ws;
    int*   ent_g  = (int*)((char*)d_ws + wt_bytes);
    int*   flag_g = (int*)((char*)d_ws + wt_bytes + ent_bytes);
    // flags are monotone within a rep; must be reset each launch (stream-ordered,
    // graph-capture-safe). ent words need no poison: flags fully gate them.
    hipMemsetAsync(flag_g, 0, flag_bytes, stream);

    transpose_k<<<64, 256, 0, stream>>>(W, WT);
    snn_kernel<<<NBATCH * NCHUNK, NTHR, 0, stream>>>(x, br, WT, pr, bbr, ent_g, flag_g, out);
}

// Round 4
// 578.444 us; speedup vs baseline: 6.7584x; 6.7584x over previous
//
#include <hip/hip_runtime.h>
#include <stdint.h>
#include <stddef.h>

#define CH     512
#define TT     32
#define NBLK   32
#define NBATCH 32
#define NCHUNK 8      // WGs per batch (64 channels each)
#define NTHR   1024   // 16 waves, 4 per SIMD

// ---- transpose: WT[j][c] = W[c][j] (row j = presyn channel, 2 KiB/row) ----
__global__ __launch_bounds__(256) void transpose_k(const float* __restrict__ W,
                                                   float* __restrict__ WT) {
    __shared__ float tile[64][65];
    const int bx = blockIdx.x & 7, by = blockIdx.x >> 3;
    const int lx = threadIdx.x & 63, ly = threadIdx.x >> 6;
    for (int r = ly; r < 64; r += 4)
        tile[r][lx] = W[(size_t)(by * 64 + r) * CH + bx * 64 + lx];
    __syncthreads();
    for (int r = ly; r < 64; r += 4)
        WT[(size_t)(bx * 64 + r) * CH + by * 64 + lx] = tile[lx][r];
}

// published word: two 16b entries [tag4 | t6 | ch6]; t=63 = no spike.
// Protocol is FENCE-FREE: the 4-bit tag lives in the SAME 32-bit word as the
// data, so a relaxed atomic load that returns the wanted tag has, by
// single-word atomicity, returned the wanted data. (R2 showed agent-scope
// fences cost 8x: vmcnt(0) drains + L1/L2 invalidation per chunk.)
// Block n publishes to parity slot (n&1); consumers of block n-1 read
// (n-1)&1. Producer j cannot rewrite parity (n-1)&1 until its block n+1,
// which is gated on consuming THIS WG's block-n publish, which follows the
// read -> no overwrite race. Rep boundary: stale tags (14 in p0, 13 in p1)
// and 0xAA poison (tag 10) are erased by each producer's block-0/1 writes
// before any consumer can want a colliding tag (wanting tag k requires having
// consumed that producer's blocks 0..k-1).
__global__ __launch_bounds__(NTHR, 4) void snn_kernel(
    const float* __restrict__ x,
    const float* __restrict__ beta_raw,
    const float* __restrict__ WT,
    const float* __restrict__ p_raw,
    const float* __restrict__ b_raw,
    int*       __restrict__ ent_g,     // [NBATCH][2][256] parity-buffered tagged words
    float*     __restrict__ out)
{
    __shared__ float rec8[8][2112];    // [gather-wave][l*33+t]; rec8[0] x-seeded
    __shared__ float rec_tot[2112];
    __shared__ int   tf_lds[64];
    __shared__ int   tmp16[64];        // producer sort scratch

    const int bidx = blockIdx.x;
    const int b    = bidx & (NBATCH - 1);   // batch's 8 WGs share an XCD
    const int kown = bidx >> 5;             // channel chunk 0..7
    const int tid  = threadIdx.x;
    const int l    = tid & 63;
    const int g    = tid >> 6;              // wave 0..15
    const size_t base = ((size_t)b) << 19;  // b*CH*1024 floats
    int* pg = ent_g + (b << 9);             // 512 words (2 parities x 256)

    const int c = (kown << 6) + l;          // wave0-lane channel
    const float beta  = fminf(fmaxf(beta_raw[c], 0.001f), 0.999f);
    const float p     = fminf(fabsf(p_raw[c]), 0.999f);
    const float bb    = fminf(fmaxf(fabsf(b_raw[c]), 0.001f), 1.0f);
    const float inv_p = 1.0f / p;
    float p32; { float t2 = p*p, t4 = t2*t2, t8 = t4*t4, t16 = t8*t8; p32 = t16*t16; }
    float a_mult = 0.f, v_init = 0.f;
    int   zero_start = 0;
    const unsigned long long lowmask = (1ull << l) - 1ull;

    // ---- pre-loop: seed rec8[0] with x block 0; zero rec8[1..7] ----
    if (tid < 512) {
        const int ch = tid >> 3, q = tid & 7;
        const float4 v = *(const float4*)(x + base + ((size_t)((kown << 6) + ch) << 10) + (q << 2));
        float* d = &rec8[0][ch * 33 + (q << 2)];
        d[0] = v.x; d[1] = v.y; d[2] = v.z; d[3] = v.w;
    } else {
        const int t0 = tid - 512;
        #pragma unroll
        for (int z = 0; z < 29; ++z) {
            const int k = t0 + (z << 9);
            if (k < 14784) (&rec8[1][0])[k] = 0.f;
        }
    }
    __syncthreads();

    for (int n = 0; n < NBLK; ++n) {
        // ---- C: waves 0-7 per-chunk spin + readlane-direct gather (chunk order
        //         0..7 fixed -> per-wave summation sequence identical to R0/R1)
        //         waves 8-15: x(n+1) prefetch + out(n-1) store ----
        float4 xstage;
        if (g >= 8) {
            const int slot = tid - 512;
            const int ch = slot >> 3, q = slot & 7;
            if (n + 1 < NBLK)
                xstage = *(const float4*)(x + base + ((size_t)((kown << 6) + ch) << 10) + ((n + 1) << 5) + (q << 2));
            if (n > 0) {
                const int tf = tf_lds[ch];
                const int t0 = q << 2;
                float4 v;
                v.x = (t0     == tf) ? 1.f : 0.f;
                v.y = (t0 + 1 == tf) ? 1.f : 0.f;
                v.z = (t0 + 2 == tf) ? 1.f : 0.f;
                v.w = (t0 + 3 == tf) ? 1.f : 0.f;
                *(float4*)(out + base + ((size_t)((kown << 6) + ch) << 10) + ((n - 1) << 5) + t0) = v;
            }
        } else if (n > 0) {
            const int* pgr = pg + (((n - 1) & 1) << 8);   // read parity
            const unsigned want = (unsigned)((n - 1) & 15);
            const int l31 = l & 31;
            const char* WTb = (const char*)WT;
            const int col4 = ((kown << 6) + l) << 2;
            float* myrec = &rec8[g][l * 33];
            int pf = 0;                 // global prefix over chunks
            float acc = 0.f; int cur_t = -1;
            #pragma unroll 1
            for (int j = 0; j < 8; ++j) {
                // spin until chunk j's 32 words all carry the wanted tag
                // (lane l holds word l&31; both wave halves load the same words)
                int wv;
                while (true) {
                    wv = __hip_atomic_load(pgr + (j << 5) + l31,
                                           __ATOMIC_RELAXED, __HIP_MEMORY_SCOPE_AGENT);
                    const unsigned v = (unsigned)wv;
                    const bool ok = ((((v >> 12) & 15u) == want) && (((v >> 28) & 15u) == want));
                    if (__all(ok)) break;
                    __builtin_amdgcn_s_sleep(1);
                }
                const int elo = wv & 0xFFFF, ehi = (wv >> 16) & 0xFFFF;
                const unsigned long long blo = __ballot((l < 32) && (((elo >> 6) & 63) != 63));
                const unsigned long long bhi = __ballot((l < 32) && (((ehi >> 6) & 63) != 63));
                const int cnt = (int)__popcll(blo) + (int)__popcll(bhi);
                // my global indices gi ≡ g (mod 8), ascending (determinism-preserving);
                // spikes-first producer sort -> chunk-local rank r lives in word r>>1, half r&1
                const int off   = (g - pf) & 7;
                const int mycnt = (cnt > off) ? ((cnt - off + 7) >> 3) : 0;
                int T[8]; float F[8];
                #pragma unroll
                for (int k = 0; k < 8; ++k) {
                    const int r  = off + (k << 3);          // chunk-local rank
                    const bool ok2 = k < mycnt;
                    const int w  = __builtin_amdgcn_readlane(wv, r >> 1);
                    const int e  = (r & 1) ? ((w >> 16) & 0xFFFF) : (w & 0xFFFF);
                    T[k] = ok2 ? ((e >> 6) & 31) : -1;
                    const int ch = ok2 ? ((j << 6) | (e & 63)) : 0;
                    F[k] = *(const float*)(WTb + (ch << 11) + col4);
                }
                #pragma unroll
                for (int k = 0; k < 8; ++k) {
                    if (T[k] >= 0) {
                        if (T[k] != cur_t) { if (cur_t >= 0) myrec[cur_t] += acc; acc = 0.f; cur_t = T[k]; }
                        acc += F[k];
                    }
                }
                pf += cnt;
            }
            if (cur_t >= 0) myrec[cur_t] += acc;
        }
        __syncthreads();   // B3: partials complete

        // ---- D: reduce 8 partials (x seeded in rec8[0]); all 1024 threads ----
        #pragma unroll
        for (int r = 0; r < 2; ++r) {
            const int e = tid + (r << 10);
            const int idx = ((e >> 5) * 33) + (e & 31);
            rec_tot[idx] = ((rec8[0][idx] + rec8[1][idx]) + (rec8[2][idx] + rec8[3][idx]))
                         + ((rec8[4][idx] + rec8[5][idx]) + (rec8[6][idx] + rec8[7][idx]));
        }
        __syncthreads();   // B4: rec_tot ready

        // ---- E: dynamics+publish (wave 0, prio 1, fused spike-rank)
        //         | x-seed write (waves 8-15) | zero (waves 1-7) ----
        if (g == 0) {
            __builtin_amdgcn_s_setprio(1);
            float mem = 0.f, pc = p, pca = p;
            int t_first = -1, mypos = 0;
            unsigned prefc = 0;
            #pragma unroll
            for (int t = 0; t < TT; ++t) {
                const float rv = rec_tot[l * 33 + t];
                float cur = (t >= zero_start) ? rv : 0.f;
                if (t == 0) cur += beta * v_init;
                mem = beta * mem + cur;
                const float vth = 1.f + bb * pc * a_mult;
                const bool fire = (mem - vth > 0.f) && (t_first < 0);
                const unsigned long long bal = __ballot(fire);
                if (fire) {
                    t_first = t; pca = pc;
                    mypos = (int)prefc + (int)__popcll(bal & lowmask);
                }
                prefc += (unsigned)__popcll(bal);
                pc *= p;
            }
            if (t_first >= 0) {
                float pd = 1.f;
                for (int m = 31 - t_first; m > 0; --m) pd *= p;
                a_mult = (pca * a_mult + inv_p) * pd;
                v_init = 0.f; zero_start = t_first;
            } else {
                a_mult = p32 * a_mult;
                v_init = mem; zero_start = 0;
            }
            tf_lds[l] = t_first;
            if (n + 1 < NBLK) {
                const bool sp = (t_first >= 0);
                const unsigned long long balS = __ballot(sp);
                const int cntS = (int)prefc;
                if (!sp) mypos = cntS + (int)__popcll(~balS & lowmask);
                const int tval = sp ? t_first : 63;
                tmp16[mypos] = ((n & 15) << 12) | (tval << 6) | l;
                __threadfence_block();   // drain ds_write before cross-lane ds_read
                if (l < 32) {
                    const int wlo = tmp16[l << 1];
                    const int whi = tmp16[(l << 1) | 1];
                    __hip_atomic_store(pg + ((n & 1) << 8) + (kown << 5) + l, wlo | (whi << 16),
                                       __ATOMIC_RELAXED, __HIP_MEMORY_SCOPE_AGENT);
                }
            }
            __builtin_amdgcn_s_setprio(0);
        } else if (g >= 8) {
            if (n + 1 < NBLK) {
                const int slot = tid - 512;
                const int ch = slot >> 3, q = slot & 7;
                float* d = &rec8[0][ch * 33 + (q << 2)];
                d[0] = xstage.x; d[1] = xstage.y; d[2] = xstage.z; d[3] = xstage.w;
            }
        } else {
            if (n + 1 < NBLK) {
                const int t0 = tid - 64;
                #pragma unroll
                for (int z = 0; z < 33; ++z)
                    (&rec8[1][0])[t0 + 448 * z] = 0.f;
            }
        }
        __syncthreads();   // B5
    }

    // ---- final out block 31 ----
    if (tid < 512) {
        const int ch = tid >> 3, q = tid & 7;
        const int tf = tf_lds[ch];
        const int t0 = q << 2;
        float4 v;
        v.x = (t0     == tf) ? 1.f : 0.f;
        v.y = (t0 + 1 == tf) ? 1.f : 0.f;
        v.z = (t0 + 2 == tf) ? 1.f : 0.f;
        v.w = (t0 + 3 == tf) ? 1.f : 0.f;
        *(float4*)(out + base + ((size_t)((kown << 6) + ch) << 10) + (31 << 5) + t0) = v;
    }
}

extern "C" void kernel_launch(void* const* d_in, const int* in_sizes, int n_in,
                              void* d_out, int out_size, void* d_ws, size_t ws_size,
                              hipStream_t stream) {
    (void)in_sizes; (void)n_in; (void)out_size;
    const float* x   = (const float*)d_in[0];
    const float* br  = (const float*)d_in[1];
    const float* W   = (const float*)d_in[2];
    const float* pr  = (const float*)d_in[3];
    const float* bbr = (const float*)d_in[4];
    float* out = (float*)d_out;

    const size_t wt_bytes  = (size_t)CH * CH * sizeof(float);      // 1 MiB
    const size_t ent_bytes = (size_t)NBATCH * 512 * sizeof(int);   // 64 KiB (2 parities)
    if (ws_size < wt_bytes + ent_bytes) return;

    float* WT    = (float*)d_ws;
    int*   ent_g = (int*)((char*)d_ws + wt_bytes);
    // no memset needed: 0xAA poison tag (10) can't match the first wanted tags
    // (0 in p0, 1 in p1), and every slot is rewritten at blocks 0/1 before any
    // consumer can want a tag that collides with stale rep data (see kernel cmt)

    transpose_k<<<64, 256, 0, stream>>>(W, WT);
    snn_kernel<<<NBATCH * NCHUNK, NTHR, 0, stream>>>(x, br, WT, pr, bbr, ent_g, out);
}

// Round 5
// 557.470 us; speedup vs baseline: 7.0127x; 1.0376x over previous
//
#include <hip/hip_runtime.h>
#include <stdint.h>
#include <stddef.h>

#define CH     512
#define TT     32
#define NBLK   32
#define NBATCH 32
#define NCHUNK 8      // WGs per batch (64 channels each)
#define NTHR   1024   // 16 waves, 4 per SIMD

// ---- transpose: WT[j][c] = W[c][j] (row j = presyn channel, 2 KiB/row) ----
__global__ __launch_bounds__(256) void transpose_k(const float* __restrict__ W,
                                                   float* __restrict__ WT) {
    __shared__ float tile[64][65];
    const int bx = blockIdx.x & 7, by = blockIdx.x >> 3;
    const int lx = threadIdx.x & 63, ly = threadIdx.x >> 6;
    for (int r = ly; r < 64; r += 4)
        tile[r][lx] = W[(size_t)(by * 64 + r) * CH + bx * 64 + lx];
    __syncthreads();
    for (int r = ly; r < 64; r += 4)
        WT[(size_t)(bx * 64 + r) * CH + by * 64 + lx] = tile[lx][r];
}

// Sync protocol (fence-free, flag-based):
//   data words: [NBATCH][2][256], two 16b entries [tag4|t6|ch6] per word
//               (tags retained in the format but no longer used for sync);
//               block n -> parity slot n&1.
//   flags:      [NBATCH][16] ints (8 used, padded to 64B). flag[k] = m means
//               chunk k has published blocks 0..m-1 this rep (monotone).
//   producer:   32 relaxed agent-scope data stores (bypass L1) ->
//               s_waitcnt vmcnt(0) (wave-level drain: stores at coherence
//               point; NOT a cache-invalidating fence, cf. R2's 8x blowup) ->
//               relaxed flag store. Flag observed => data visible.
//   consumer:   spins on the 8 flags concurrently (1 load/lane/iter, 2 lines
//               per batch -> no poll storm on the data lines), then reads the
//               256 data words once, prefetched 8-deep.
//   overwrite safety: producer k rewrites parity (n-1)&1 only at its block
//               n+1 publish, which is gated on observing THIS WG's block-n
//               flag, which is stored after B3/B4 barriers drained this WG's
//               block-(n-1) data reads -> no race. Monotone flags + per-launch
//               memsetAsync reset kill all tag-wrap/poison/replay edge cases.
__global__ __launch_bounds__(NTHR, 4) void snn_kernel(
    const float* __restrict__ x,
    const float* __restrict__ beta_raw,
    const float* __restrict__ WT,
    const float* __restrict__ p_raw,
    const float* __restrict__ b_raw,
    int*       __restrict__ ent_g,     // [NBATCH][2][256] parity-buffered words
    int*       __restrict__ flag_g,    // [NBATCH][16] padded monotone flags
    float*     __restrict__ out)
{
    __shared__ float rec8[8][2112];    // [gather-wave][l*33+t]; rec8[0] x-seeded
    __shared__ float rec_tot[2112];
    __shared__ int   tf_lds[64];
    __shared__ int   tmp16[64];        // producer sort scratch

    const int bidx = blockIdx.x;
    const int b    = bidx & (NBATCH - 1);   // batch's 8 WGs share an XCD residue
    const int kown = bidx >> 5;             // channel chunk 0..7
    const int tid  = threadIdx.x;
    const int l    = tid & 63;
    const int g    = tid >> 6;              // wave 0..15
    const size_t base = ((size_t)b) << 19;  // b*CH*1024 floats
    int* pg = ent_g  + (b << 9);            // 512 words (2 parities x 256)
    int* fg = flag_g + (b << 4);

    const int c = (kown << 6) + l;          // wave0-lane channel
    const float beta  = fminf(fmaxf(beta_raw[c], 0.001f), 0.999f);
    const float p     = fminf(fabsf(p_raw[c]), 0.999f);
    const float bb    = fminf(fmaxf(fabsf(b_raw[c]), 0.001f), 1.0f);
    const float inv_p = 1.0f / p;
    float p32; { float t2 = p*p, t4 = t2*t2, t8 = t4*t4, t16 = t8*t8; p32 = t16*t16; }
    float a_mult = 0.f, v_init = 0.f;
    int   zero_start = 0;
    const unsigned long long lowmask = (1ull << l) - 1ull;

    // ---- pre-loop: seed rec8[0] with x block 0; zero rec8[1..7] ----
    if (tid < 512) {
        const int ch = tid >> 3, q = tid & 7;
        const float4 v = *(const float4*)(x + base + ((size_t)((kown << 6) + ch) << 10) + (q << 2));
        float* d = &rec8[0][ch * 33 + (q << 2)];
        d[0] = v.x; d[1] = v.y; d[2] = v.z; d[3] = v.w;
    } else {
        const int t0 = tid - 512;
        #pragma unroll
        for (int z = 0; z < 29; ++z) {
            const int k = t0 + (z << 9);
            if (k < 14784) (&rec8[1][0])[k] = 0.f;
        }
    }
    __syncthreads();

    for (int n = 0; n < NBLK; ++n) {
        // ---- C: waves 0-7 concurrent flag spin + prefetched readlane gather
        //         (chunk processing order 0..7 fixed -> per-wave summation
        //          sequence identical to R0/R1/R4, proven absmax 0.0)
        //         waves 8-15: x(n+1) prefetch + out(n-1) store ----
        float4 xstage;
        if (g >= 8) {
            const int slot = tid - 512;
            const int ch = slot >> 3, q = slot & 7;
            if (n + 1 < NBLK)
                xstage = *(const float4*)(x + base + ((size_t)((kown << 6) + ch) << 10) + ((n + 1) << 5) + (q << 2));
            if (n > 0) {
                const int tf = tf_lds[ch];
                const int t0 = q << 2;
                float4 v;
                v.x = (t0     == tf) ? 1.f : 0.f;
                v.y = (t0 + 1 == tf) ? 1.f : 0.f;
                v.z = (t0 + 2 == tf) ? 1.f : 0.f;
                v.w = (t0 + 3 == tf) ? 1.f : 0.f;
                *(float4*)(out + base + ((size_t)((kown << 6) + ch) << 10) + ((n - 1) << 5) + t0) = v;
            }
        } else if (n > 0) {
            // -- concurrent spin on all 8 chunk flags (lane l watches flag l&7)
            {
                const int myf = l & 7;
                while (true) {
                    const int fv = __hip_atomic_load(fg + myf, __ATOMIC_RELAXED, __HIP_MEMORY_SCOPE_AGENT);
                    if (__all(fv >= n)) break;
                    __builtin_amdgcn_s_sleep(1);
                }
            }
            asm volatile("" ::: "memory");   // no compiler hoist of data loads above spin
            const int* pgr = pg + (((n - 1) & 1) << 8);   // read parity
            const int l31 = l & 31;
            // -- prefetch all 8 chunk words (8 independent loads in flight)
            int wv[8];
            #pragma unroll
            for (int j = 0; j < 8; ++j)
                wv[j] = __hip_atomic_load(pgr + (j << 5) + l31,
                                          __ATOMIC_RELAXED, __HIP_MEMORY_SCOPE_AGENT);
            const char* WTb = (const char*)WT;
            const int col4 = ((kown << 6) + l) << 2;
            float* myrec = &rec8[g][l * 33];
            int pf = 0;                 // global prefix over chunks
            float acc = 0.f; int cur_t = -1;
            #pragma unroll
            for (int j = 0; j < 8; ++j) {
                const int w_ = wv[j];
                const int elo = w_ & 0xFFFF, ehi = (w_ >> 16) & 0xFFFF;
                const unsigned long long blo = __ballot((l < 32) && (((elo >> 6) & 63) != 63));
                const unsigned long long bhi = __ballot((l < 32) && (((ehi >> 6) & 63) != 63));
                const int cnt = (int)__popcll(blo) + (int)__popcll(bhi);
                // my global indices gi ≡ g (mod 8), ascending (determinism-preserving);
                // spikes-first producer sort -> chunk-local rank r in word r>>1, half r&1
                const int off   = (g - pf) & 7;
                const int mycnt = (cnt > off) ? ((cnt - off + 7) >> 3) : 0;
                int T[8]; float F[8];
                #pragma unroll
                for (int k = 0; k < 8; ++k) {
                    const int r  = off + (k << 3);          // chunk-local rank
                    const bool ok2 = k < mycnt;
                    const int w2 = __builtin_amdgcn_readlane(wv[j], r >> 1);
                    const int e  = (r & 1) ? ((w2 >> 16) & 0xFFFF) : (w2 & 0xFFFF);
                    T[k] = ok2 ? ((e >> 6) & 31) : -1;
                    const int ch = ok2 ? ((j << 6) | (e & 63)) : 0;
                    F[k] = *(const float*)(WTb + (ch << 11) + col4);
                }
                #pragma unroll
                for (int k = 0; k < 8; ++k) {
                    if (T[k] >= 0) {
                        if (T[k] != cur_t) { if (cur_t >= 0) myrec[cur_t] += acc; acc = 0.f; cur_t = T[k]; }
                        acc += F[k];
                    }
                }
                pf += cnt;
            }
            if (cur_t >= 0) myrec[cur_t] += acc;
        }
        __syncthreads();   // B3: partials complete

        // ---- D: reduce 8 partials (x seeded in rec8[0]); all 1024 threads ----
        #pragma unroll
        for (int r = 0; r < 2; ++r) {
            const int e = tid + (r << 10);
            const int idx = ((e >> 5) * 33) + (e & 31);
            rec_tot[idx] = ((rec8[0][idx] + rec8[1][idx]) + (rec8[2][idx] + rec8[3][idx]))
                         + ((rec8[4][idx] + rec8[5][idx]) + (rec8[6][idx] + rec8[7][idx]));
        }
        __syncthreads();   // B4: rec_tot ready

        // ---- E: dynamics+publish (wave 0, prio 1, fused spike-rank)
        //         | x-seed write (waves 8-15) | zero (waves 1-7) ----
        if (g == 0) {
            __builtin_amdgcn_s_setprio(1);
            float mem = 0.f, pc = p, pca = p;
            int t_first = -1, mypos = 0;
            unsigned prefc = 0;
            #pragma unroll
            for (int t = 0; t < TT; ++t) {
                const float rv = rec_tot[l * 33 + t];
                float cur = (t >= zero_start) ? rv : 0.f;
                if (t == 0) cur += beta * v_init;
                mem = beta * mem + cur;
                const float vth = 1.f + bb * pc * a_mult;
                const bool fire = (mem - vth > 0.f) && (t_first < 0);
                const unsigned long long bal = __ballot(fire);
                if (fire) {
                    t_first = t; pca = pc;
                    mypos = (int)prefc + (int)__popcll(bal & lowmask);
                }
                prefc += (unsigned)__popcll(bal);
                pc *= p;
            }
            if (t_first >= 0) {
                float pd = 1.f;
                for (int m = 31 - t_first; m > 0; --m) pd *= p;
                a_mult = (pca * a_mult + inv_p) * pd;
                v_init = 0.f; zero_start = t_first;
            } else {
                a_mult = p32 * a_mult;
                v_init = mem; zero_start = 0;
            }
            tf_lds[l] = t_first;
            if (n + 1 < NBLK) {
                const bool sp = (t_first >= 0);
                const unsigned long long balS = __ballot(sp);
                const int cntS = (int)prefc;
                if (!sp) mypos = cntS + (int)__popcll(~balS & lowmask);
                const int tval = sp ? t_first : 63;
                tmp16[mypos] = ((n & 15) << 12) | (tval << 6) | l;
                __threadfence_block();   // drain ds_write before cross-lane ds_read
                if (l < 32) {
                    const int wlo = tmp16[l << 1];
                    const int whi = tmp16[(l << 1) | 1];
                    __hip_atomic_store(pg + ((n & 1) << 8) + (kown << 5) + l, wlo | (whi << 16),
                                       __ATOMIC_RELAXED, __HIP_MEMORY_SCOPE_AGENT);
                }
                // release: wave-level drain of the data stores (cheap; no cache inval)
                asm volatile("s_waitcnt vmcnt(0)" ::: "memory");
                if (l == 0)
                    __hip_atomic_store(fg + kown, n + 1,
                                       __ATOMIC_RELAXED, __HIP_MEMORY_SCOPE_AGENT);
            }
            __builtin_amdgcn_s_setprio(0);
        } else if (g >= 8) {
            if (n + 1 < NBLK) {
                const int slot = tid - 512;
                const int ch = slot >> 3, q = slot & 7;
                float* d = &rec8[0][ch * 33 + (q << 2)];
                d[0] = xstage.x; d[1] = xstage.y; d[2] = xstage.z; d[3] = xstage.w;
            }
        } else {
            if (n + 1 < NBLK) {
                const int t0 = tid - 64;
                #pragma unroll
                for (int z = 0; z < 33; ++z)
                    (&rec8[1][0])[t0 + 448 * z] = 0.f;
            }
        }
        __syncthreads();   // B5
    }

    // ---- final out block 31 ----
    if (tid < 512) {
        const int ch = tid >> 3, q = tid & 7;
        const int tf = tf_lds[ch];
        const int t0 = q << 2;
        float4 v;
        v.x = (t0     == tf) ? 1.f : 0.f;
        v.y = (t0 + 1 == tf) ? 1.f : 0.f;
        v.z = (t0 + 2 == tf) ? 1.f : 0.f;
        v.w = (t0 + 3 == tf) ? 1.f : 0.f;
        *(float4*)(out + base + ((size_t)((kown << 6) + ch) << 10) + (31 << 5) + t0) = v;
    }
}

extern "C" void kernel_launch(void* const* d_in, const int* in_sizes, int n_in,
                              void* d_out, int out_size, void* d_ws, size_t ws_size,
                              hipStream_t stream) {
    (void)in_sizes; (void)n_in; (void)out_size;
    const float* x   = (const float*)d_in[0];
    const float* br  = (const float*)d_in[1];
    const float* W   = (const float*)d_in[2];
    const float* pr  = (const float*)d_in[3];
    const float* bbr = (const float*)d_in[4];
    float* out = (float*)d_out;

    const size_t wt_bytes   = (size_t)CH * CH * sizeof(float);      // 1 MiB
    const size_t ent_bytes  = (size_t)NBATCH * 512 * sizeof(int);   // 64 KiB (2 parities)
    const size_t flag_bytes = (size_t)NBATCH * 16 * sizeof(int);    // 2 KiB
    if (ws_size < wt_bytes + ent_bytes + flag_bytes) return;

    float* WT     = (float*)d_ws;
    int*   ent_g  = (int*)((char*)d_ws + wt_bytes);
    int*   flag_g = (int*)((char*)d_ws + wt_bytes + ent_bytes);
    // monotone flags must start at 0 each launch (stream-ordered, graph-safe)
    hipMemsetAsync(flag_g, 0, flag_bytes, stream);

    transpose_k<<<64, 256, 0, stream>>>(W, WT);
    snn_kernel<<<NBATCH * NCHUNK, NTHR, 0, stream>>>(x, br, WT, pr, bbr, ent_g, flag_g, out);
}